// Round 6
// baseline (1287.293 us; speedup 1.0000x reference)
//
#include <hip/hip_runtime.h>
#include <hip/hip_bf16.h>

typedef __attribute__((ext_vector_type(4))) float  f32x4;
typedef __attribute__((ext_vector_type(8))) short  bf16x8;
typedef __attribute__((ext_vector_type(4))) int    i32x4;

#define M_DIM 8192
#define N_DIM 11008
#define K_DIM 4096
#define KP    2048

#define A_WS_BYTES ((size_t)M_DIM * K_DIM * 2)
#define B_WS_BYTES ((size_t)N_DIM * K_DIM * 2)
#define WS_NEED    (A_WS_BYTES + B_WS_BYTES)

// ---- 256x256 tile, BK=64, 8 waves (2Mx4N); A in LDS (4-deep), B direct-to-reg ----
#define BM 256
#define BN 256
#define BK 64
#define NT (K_DIM / BK)        // 64 K-tiles
#define ATILE_BYTES 32768      // 256 rows x 64 cols x 2B
// LDS total: 4 * 32768 = 131072

__device__ __forceinline__ short f2bf(float f) {
    return __builtin_bit_cast(short, __float2bfloat16(f));
}

// ---------------- prepass: x fp32 -> bf16 ----------------
__global__ __launch_bounds__(256)
void cvt_x_kernel(const float* __restrict__ x, short* __restrict__ xb)
{
    const size_t i = ((size_t)blockIdx.x * 256 + threadIdx.x) * 8;
    const f32x4 a = *(const f32x4*)(x + i);
    const f32x4 b = *(const f32x4*)(x + i + 4);
    bf16x8 o;
    #pragma unroll
    for (int j = 0; j < 4; ++j) {
        o[j]     = f2bf(a[j]);
        o[4 + j] = f2bf(b[j]);
    }
    *(bf16x8*)(xb + i) = o;
}

// ---------------- prepass: packed int4 -> bf16 ----------------
__global__ __launch_bounds__(256)
void dequant_w_kernel(const int* __restrict__ wq, short* __restrict__ wb)
{
    const size_t i = ((size_t)blockIdx.x * 256 + threadIdx.x) * 4;
    const i32x4 v = *(const i32x4*)(wq + i);
    bf16x8 o;
    #pragma unroll
    for (int j = 0; j < 4; ++j) {
        const int q = (v[j] & 0xFF) ^ 0x88;
        o[2 * j]     = f2bf((float)((q & 15) - 8));
        o[2 * j + 1] = f2bf((float)(((q >> 4) & 15) - 8));
    }
    *(bf16x8*)(wb + i * 2) = o;
}

// ---------------- main GEMM: A-LDS 4-deep + B-direct-to-reg, 1 barrier/K-tile ----------------
__global__ __launch_bounds__(512, 2)
void gemm256_kernel(const short* __restrict__ A,     // [8192][4096] bf16
                    const short* __restrict__ Bw,    // [11008][4096] bf16
                    const float* __restrict__ scale,
                    const float* __restrict__ bias,
                    float* __restrict__ out)
{
    __shared__ char lds[4 * ATILE_BYTES];   // 128 KiB, A tiles only

    const int t    = threadIdx.x;
    const int lane = t & 63;
    const int wv   = t >> 6;          // 0..7
    const int wm   = wv >> 2;         // 0..1 -> M half (128 rows)
    const int wn   = wv & 3;          // 0..3 -> N quarter (64 cols)

    // bijective XCD chunk swizzle (nwg = 1376, %8 == 0)
    const int nbx = N_DIM / BN;                       // 43
    const int cpx = (nbx * (M_DIM / BM)) >> 3;        // 172
    const int bid = blockIdx.x;
    const int sid = (bid & 7) * cpx + (bid >> 3);
    const int by  = sid / nbx;
    const int bx  = sid - by * nbx;
    const int m0  = by * BM;
    const int n0  = bx * BN;

    // ---- A staging: thread t covers rows (t>>3)+64*i, physical granule t&7 ----
    // LDS phys (row, g) holds logical granule g ^ (row&7); source pre-swizzled (rule #21).
    const int srow = t >> 3;                               // 0..63
    const int scol = ((t & 7) ^ (srow & 7)) * 8;           // element offset in row
    const short* aS = A + (size_t)(m0 + srow) * K_DIM + scol;

#define STAGE_A(kt_) do {                                                               \
    const int b_ = (kt_) & 3;                                                           \
    _Pragma("unroll")                                                                   \
    for (int i_ = 0; i_ < 4; ++i_)                                                      \
        __builtin_amdgcn_global_load_lds(                                               \
            (const __attribute__((address_space(1))) unsigned int*)                     \
                (aS + (size_t)(i_ * 64) * K_DIM + (kt_) * BK),                          \
            (__attribute__((address_space(3))) unsigned int*)                           \
                (lds + b_ * ATILE_BYTES + i_ * 8192 + t * 16),                          \
            16, 0, 0);                                                                  \
} while (0)

    // ---- A fragment read offsets (swizzled; ks1 = offset ^ 64, XOR-safe) ----
    const int lr = lane & 15;
    const int lk = lane >> 4;
    int aOff[8];
    #pragma unroll
    for (int mi = 0; mi < 8; ++mi) {
        const int row = wm * 128 + mi * 16 + lr;
        aOff[mi] = row * 128 + ((lk ^ (row & 7)) * 16);
    }

    // ---- B fragment global pointers: per (ni) base; k = kt*64 + ks*32 + lk*8 ----
    const short* bgl[4];
    #pragma unroll
    for (int ni = 0; ni < 4; ++ni)
        bgl[ni] = Bw + (size_t)(n0 + wn * 64 + ni * 16 + lr) * K_DIM + lk * 8;

    bf16x8 breg[2][4][2];   // [parity][ni][ks]

#define LOADB(P, kt_) do {                                                              \
    _Pragma("unroll")                                                                   \
    for (int n_ = 0; n_ < 4; ++n_)                                                      \
        _Pragma("unroll")                                                               \
        for (int k_ = 0; k_ < 2; ++k_)                                                  \
            breg[P][n_][k_] = *(const bf16x8*)(bgl[n_] + (kt_) * BK + k_ * 32);         \
} while (0)

    f32x4 acc[8][4];
    #pragma unroll
    for (int mi = 0; mi < 8; ++mi)
        #pragma unroll
        for (int ni = 0; ni < 4; ++ni)
            acc[mi][ni] = (f32x4){0.f, 0.f, 0.f, 0.f};

    // quadrant cluster: read 4 A-frags (one ks), 16 MFMA
#define QCLUST(BUFP, MIBASE, KS, P) do {                                                \
    bf16x8 af_[4];                                                                      \
    _Pragma("unroll")                                                                   \
    for (int m_ = 0; m_ < 4; ++m_)                                                      \
        af_[m_] = *(const bf16x8*)((BUFP) + (aOff[(MIBASE) + m_] ^ ((KS) * 64)));       \
    __builtin_amdgcn_s_setprio(1);                                                      \
    _Pragma("unroll")                                                                   \
    for (int m_ = 0; m_ < 4; ++m_)                                                      \
        _Pragma("unroll")                                                               \
        for (int n_ = 0; n_ < 4; ++n_)                                                  \
            acc[(MIBASE) + m_][n_] = __builtin_amdgcn_mfma_f32_16x16x32_bf16(           \
                af_[m_], breg[P][n_][KS], acc[(MIBASE) + m_][n_], 0, 0, 0);             \
    __builtin_amdgcn_s_setprio(0);                                                      \
} while (0)

    // ---- prologue: stage A tiles 0..2, load B(0); wait A(0); barrier ----
    STAGE_A(0); STAGE_A(1); STAGE_A(2);
    LOADB(0, 0);
    asm volatile("s_waitcnt vmcnt(16)" ::: "memory");   // 20 out; drain A(0)'s 4
    __builtin_amdgcn_s_barrier();

    // ---- main loop: 1 barrier per K-tile; compiler emits tight counted vmcnt for B ----
    for (int kt0 = 0; kt0 < NT; kt0 += 4) {
        #pragma unroll
        for (int u = 0; u < 4; ++u) {
            const int kt = kt0 + u;
            const char* buf = lds + u * ATILE_BYTES;
            if (kt + 3 < NT) STAGE_A(kt + 3);           // dest buffer sealed by barrier(kt-1)
            if (kt + 1 < NT) LOADB((u + 1) & 1, kt + 1);
            QCLUST(buf, 0, 0, u & 1);
            QCLUST(buf, 0, 1, u & 1);
            QCLUST(buf, 4, 0, u & 1);
            QCLUST(buf, 4, 1, u & 1);
            __builtin_amdgcn_s_barrier();
        }
    }

    // ---- epilogue: out = acc * scale[n] + bias[n] ----
    // C/D layout: col = lane&15, row = (lane>>4)*4 + reg   (verified, passing R1-R5)
    #pragma unroll
    for (int ni = 0; ni < 4; ++ni) {
        const int gn = n0 + wn * 64 + ni * 16 + lr;
        const float sc = scale[gn];
        const float bi = bias[gn];
        #pragma unroll
        for (int mi = 0; mi < 8; ++mi) {
            const int gm = m0 + wm * 128 + mi * 16 + lk * 4;
            const f32x4 v = acc[mi][ni];
            #pragma unroll
            for (int r = 0; r < 4; ++r)
                out[(size_t)(gm + r) * N_DIM + gn] = v[r] * sc + bi;
        }
    }
#undef STAGE_A
#undef LOADB
#undef QCLUST
}

// ---------------- fallback: fused dequant GEMM (R1 kernel, known-good) ----------------
__device__ __forceinline__ int swz(int row, int kbyte) {
    return row * 128 + (kbyte ^ ((row & 7) << 4));
}

__global__ __launch_bounds__(256, 2)
void qlin_kernel(const float* __restrict__ x,
                 const int*   __restrict__ wq,
                 const float* __restrict__ scale,
                 const float* __restrict__ bias,
                 float* __restrict__ out)
{
    __shared__ short As[128 * 64];
    __shared__ short Bs[128 * 64];

    const int t  = threadIdx.x;
    const int n0 = blockIdx.x * 128;
    const int m0 = blockIdx.y * 128;

    const int sr = t >> 1;
    const int sh = t & 1;

    const float* ag = x  + (size_t)(m0 + sr) * K_DIM + sh * 32;
    const int*   bg = wq + (size_t)(n0 + sr) * KP    + sh * 16;

    const int lane = t & 63;
    const int wv   = t >> 6;
    const int wm   = wv >> 1;
    const int wn   = wv & 1;
    const int lr   = lane & 15;
    const int lk   = lane >> 4;

    f32x4 acc[4][4];
    #pragma unroll
    for (int i = 0; i < 4; ++i)
        #pragma unroll
        for (int j = 0; j < 4; ++j)
            acc[i][j] = (f32x4){0.f, 0.f, 0.f, 0.f};

    f32x4 ar[8];
    i32x4 br[4];

    #pragma unroll
    for (int i = 0; i < 8; ++i) ar[i] = *(const f32x4*)(ag + i * 4);
    #pragma unroll
    for (int i = 0; i < 4; ++i) br[i] = *(const i32x4*)(bg + i * 4);

    for (int kt = 0; kt < 64; ++kt) {
        #pragma unroll
        for (int c = 0; c < 4; ++c) {
            bf16x8 pa;
            #pragma unroll
            for (int j = 0; j < 8; ++j)
                pa[j] = f2bf(ar[c * 2 + (j >> 2)][j & 3]);
            *(bf16x8*)((char*)As + swz(sr, sh * 64 + c * 16)) = pa;

            bf16x8 pb;
            #pragma unroll
            for (int j = 0; j < 4; ++j) {
                const int q = br[c][j] ^ 0x88;
                const float flo = __builtin_bit_cast(float, 0x4B000000 | (q & 15))        - 8388616.0f;
                const float fhi = __builtin_bit_cast(float, 0x4B000000 | ((q >> 4) & 15)) - 8388616.0f;
                pb[2 * j]     = f2bf(flo);
                pb[2 * j + 1] = f2bf(fhi);
            }
            *(bf16x8*)((char*)Bs + swz(sr, sh * 64 + c * 16)) = pb;
        }
        __syncthreads();

        if (kt + 1 < 64) {
            const float* an = ag + (kt + 1) * 64;
            const int*   bn = bg + (kt + 1) * 32;
            #pragma unroll
            for (int i = 0; i < 8; ++i) ar[i] = *(const f32x4*)(an + i * 4);
            #pragma unroll
            for (int i = 0; i < 4; ++i) br[i] = *(const i32x4*)(bn + i * 4);
        }

        #pragma unroll
        for (int ks = 0; ks < 2; ++ks) {
            const int kb = ks * 64 + lk * 16;
            bf16x8 af2[4], bf2[4];
            #pragma unroll
            for (int mi = 0; mi < 4; ++mi)
                af2[mi] = *(const bf16x8*)((const char*)As + swz(wm * 64 + mi * 16 + lr, kb));
            #pragma unroll
            for (int ni = 0; ni < 4; ++ni)
                bf2[ni] = *(const bf16x8*)((const char*)Bs + swz(wn * 64 + ni * 16 + lr, kb));
            #pragma unroll
            for (int mi = 0; mi < 4; ++mi)
                #pragma unroll
                for (int ni = 0; ni < 4; ++ni)
                    acc[mi][ni] = __builtin_amdgcn_mfma_f32_16x16x32_bf16(
                        af2[mi], bf2[ni], acc[mi][ni], 0, 0, 0);
        }
        __syncthreads();
    }

    #pragma unroll
    for (int ni = 0; ni < 4; ++ni) {
        const int gn = n0 + wn * 64 + ni * 16 + lr;
        const float sc = scale[gn];
        const float bi = bias[gn];
        #pragma unroll
        for (int mi = 0; mi < 4; ++mi) {
            const int gm = m0 + wm * 64 + mi * 16 + lk * 4;
            const f32x4 v = acc[mi][ni];
            #pragma unroll
            for (int r2 = 0; r2 < 4; ++r2)
                out[(size_t)(gm + r2) * N_DIM + gn] = v[r2] * sc + bi;
        }
    }
}

extern "C" void kernel_launch(void* const* d_in, const int* in_sizes, int n_in,
                              void* d_out, int out_size, void* d_ws, size_t ws_size,
                              hipStream_t stream)
{
    const float* x     = (const float*)d_in[0];
    const int*   wq    = (const int*)d_in[1];
    const float* scale = (const float*)d_in[2];
    const float* bias  = (const float*)d_in[3];
    float*       out   = (float*)d_out;

    if (ws_size >= WS_NEED) {
        short* xb = (short*)d_ws;
        short* wb = (short*)((char*)d_ws + A_WS_BYTES);
        cvt_x_kernel<<<16384, 256, 0, stream>>>(x, xb);
        dequant_w_kernel<<<22016, 256, 0, stream>>>(wq, wb);
        const int nwg = (N_DIM / BN) * (M_DIM / BM);   // 43*32 = 1376
        gemm256_kernel<<<nwg, 512, 0, stream>>>(xb, wb, scale, bias, out);
    } else {
        qlin_kernel<<<dim3(N_DIM / 128, M_DIM / 128), 256, 0, stream>>>(x, wq, scale, bias, out);
    }
}

// Round 7
// 876.243 us; speedup vs baseline: 1.4691x; 1.4691x over previous
//
#include <hip/hip_runtime.h>
#include <hip/hip_bf16.h>

typedef __attribute__((ext_vector_type(4))) float  f32x4;
typedef __attribute__((ext_vector_type(8))) short  bf16x8;
typedef __attribute__((ext_vector_type(4))) int    i32x4;

#define M_DIM 8192
#define N_DIM 11008
#define K_DIM 4096
#define KP    2048

#define A_WS_BYTES ((size_t)M_DIM * K_DIM * 2)
#define B_WS_BYTES ((size_t)N_DIM * K_DIM * 2)
#define WS_NEED    (A_WS_BYTES + B_WS_BYTES)

// ---- 256x256 tile, BK=64, 8 waves (2Mx4N); A in LDS (4-deep), B frag-major from L2 ----
#define BM 256
#define BN 256
#define BK 64
#define NT (K_DIM / BK)        // 64 K-tiles
#define ATILE_BYTES 32768      // 256 rows x 64 cols x 2B
// LDS total: 4 * 32768 = 131072

__device__ __forceinline__ short f2bf(float f) {
    return __builtin_bit_cast(short, __float2bfloat16(f));
}

// ---------------- prepass: x fp32 -> bf16 ----------------
__global__ __launch_bounds__(256)
void cvt_x_kernel(const float* __restrict__ x, short* __restrict__ xb)
{
    const size_t i = ((size_t)blockIdx.x * 256 + threadIdx.x) * 8;
    const f32x4 a = *(const f32x4*)(x + i);
    const f32x4 b = *(const f32x4*)(x + i + 4);
    bf16x8 o;
    #pragma unroll
    for (int j = 0; j < 4; ++j) {
        o[j]     = f2bf(a[j]);
        o[4 + j] = f2bf(b[j]);
    }
    *(bf16x8*)(xb + i) = o;
}

// ---------------- prepass: packed int4 -> bf16, FRAGMENT-MAJOR layout ----------------
// B'[n16][c=kt*2+ks] = 1024B block; byte (lane*16) = lane's MFMA B-frag:
//   lane = lk*16+lr -> n = n16*16+lr, k = c*32 + lk*8 + j  (j=0..7)
__global__ __launch_bounds__(256)
void dequant_w_frag(const int* __restrict__ wq, short* __restrict__ wb)
{
    const int w    = (blockIdx.x * 256 + threadIdx.x) >> 6;  // wave id, 0..88063
    const int lane = threadIdx.x & 63;
    const int n16  = w >> 7;          // 0..687
    const int c    = w & 127;         // 0..127
    const int q    = lane >> 4;       // lk
    const int lr   = lane & 15;

    // read 4 int32 (= 8 k) at k = c*32 + q*8
    const i32x4 v = *(const i32x4*)(wq + (size_t)(n16 * 16 + lr) * KP + c * 16 + q * 4);
    bf16x8 o;
    #pragma unroll
    for (int m = 0; m < 4; ++m) {
        const int b = (v[m] & 0xFF) ^ 0x88;                 // xor both nibbles with 8
        o[2 * m]     = f2bf((float)((b & 15) - 8));         // even k = low nibble
        o[2 * m + 1] = f2bf((float)(((b >> 4) & 15) - 8));  // odd  k = high nibble
    }
    *(bf16x8*)((char*)wb + (((size_t)(n16 * 128 + c)) << 10) + lane * 16) = o;
}

// ---------------- main GEMM: A-LDS 4-deep + frag-major B direct-to-reg ----------------
__global__ __launch_bounds__(512, 2)
void gemm256_kernel(const short* __restrict__ A,     // [8192][4096] bf16
                    const char*  __restrict__ Bp,    // frag-major B'
                    const float* __restrict__ scale,
                    const float* __restrict__ bias,
                    float* __restrict__ out)
{
    __shared__ char lds[4 * ATILE_BYTES];   // 128 KiB, A tiles only

    const int t    = threadIdx.x;
    const int lane = t & 63;
    const int wv   = t >> 6;          // 0..7
    const int wm   = wv >> 2;         // 0..1 -> M half (128 rows)
    const int wn   = wv & 3;          // 0..3 -> N quarter (64 cols)

    // bijective XCD chunk swizzle (nwg = 1376, %8 == 0)
    const int nbx = N_DIM / BN;                       // 43
    const int cpx = (nbx * (M_DIM / BM)) >> 3;        // 172
    const int bid = blockIdx.x;
    const int sid = (bid & 7) * cpx + (bid >> 3);
    const int by  = sid / nbx;
    const int bx  = sid - by * nbx;
    const int m0  = by * BM;
    const int n0  = bx * BN;

    // ---- A staging: thread t covers rows (t>>3)+64*i, physical granule t&7 ----
    // LDS phys (row, g) holds logical granule g ^ (row&7); source pre-swizzled (rule #21).
    const int srow = t >> 3;                               // 0..63
    const int scol = ((t & 7) ^ (srow & 7)) * 8;           // element offset in row
    const short* aS = A + (size_t)(m0 + srow) * K_DIM + scol;

#define STAGE_A(kt_) do {                                                               \
    const int b_ = (kt_) & 3;                                                           \
    _Pragma("unroll")                                                                   \
    for (int i_ = 0; i_ < 4; ++i_)                                                      \
        __builtin_amdgcn_global_load_lds(                                               \
            (const __attribute__((address_space(1))) unsigned int*)                     \
                (aS + (size_t)(i_ * 64) * K_DIM + (kt_) * BK),                          \
            (__attribute__((address_space(3))) unsigned int*)                           \
                (lds + b_ * ATILE_BYTES + i_ * 8192 + t * 16),                          \
            16, 0, 0);                                                                  \
} while (0)

    // ---- A fragment read offsets (swizzled; ks1 = offset ^ 64) ----
    const int lr = lane & 15;
    const int lk = lane >> 4;
    int aOff[8];
    #pragma unroll
    for (int mi = 0; mi < 8; ++mi) {
        const int row = wm * 128 + mi * 16 + lr;
        aOff[mi] = row * 128 + ((lk ^ (row & 7)) * 16);
    }

    // ---- B fragment pointers: per ni, contiguous 1024B/wave blocks ----
    const char* bP[4];
    #pragma unroll
    for (int ni = 0; ni < 4; ++ni)
        bP[ni] = Bp + (((size_t)(bx * 16 + wn * 4 + ni)) << 17) + (size_t)lane * 16;

    bf16x8 breg[2][4][2];   // [parity][ni][ks]

#define LOADB(P, kt_) do {                                                              \
    _Pragma("unroll")                                                                   \
    for (int n_ = 0; n_ < 4; ++n_)                                                      \
        _Pragma("unroll")                                                               \
        for (int k_ = 0; k_ < 2; ++k_)                                                  \
            breg[P][n_][k_] = *(const bf16x8*)(bP[n_] + (((kt_) * 2 + k_) << 10));      \
} while (0)

    f32x4 acc[8][4];
    #pragma unroll
    for (int mi = 0; mi < 8; ++mi)
        #pragma unroll
        for (int ni = 0; ni < 4; ++ni)
            acc[mi][ni] = (f32x4){0.f, 0.f, 0.f, 0.f};

    // quadrant cluster: read 4 A-frags (one ks), 16 MFMA
#define QCLUST(BUFP, MIBASE, KS, P) do {                                                \
    bf16x8 af_[4];                                                                      \
    _Pragma("unroll")                                                                   \
    for (int m_ = 0; m_ < 4; ++m_)                                                      \
        af_[m_] = *(const bf16x8*)((BUFP) + (aOff[(MIBASE) + m_] ^ ((KS) * 64)));       \
    __builtin_amdgcn_s_setprio(1);                                                      \
    _Pragma("unroll")                                                                   \
    for (int m_ = 0; m_ < 4; ++m_)                                                      \
        _Pragma("unroll")                                                               \
        for (int n_ = 0; n_ < 4; ++n_)                                                  \
            acc[(MIBASE) + m_][n_] = __builtin_amdgcn_mfma_f32_16x16x32_bf16(           \
                af_[m_], breg[P][n_][KS], acc[(MIBASE) + m_][n_], 0, 0, 0);             \
    __builtin_amdgcn_s_setprio(0);                                                      \
} while (0)

#define VMC(N) asm volatile("s_waitcnt vmcnt(" #N ")" ::: "memory")

    // ---- prologue: stage A tiles 0..2 (12 loads), load B(0) (8); drain A(0) ----
    STAGE_A(0); STAGE_A(1); STAGE_A(2);
    LOADB(0, 0);
    VMC(16);                          // 20 out; newest 16 = A(1),A(2),B(0) -> A(0) done
    __builtin_amdgcn_s_barrier();

    // ---- main loop: 1 barrier/K-tile; VMC(12) ledger keeps 3 A-tiles + 1 B-tile in flight ----
    for (int kt0 = 0; kt0 < NT; kt0 += 4) {
        #pragma unroll
        for (int u = 0; u < 4; ++u) {
            const int kt = kt0 + u;
            const char* buf = lds + u * ATILE_BYTES;
            if (kt + 3 < NT) STAGE_A(kt + 3);      // dest buffer freed by barrier(kt-1)
            if (kt + 1 < NT) LOADB((u + 1) & 1, kt + 1);
            VMC(12);                               // newest 12 = A(kt+3)+B(kt+1); A(kt) drained
            QCLUST(buf, 0, 0, u & 1);
            QCLUST(buf, 0, 1, u & 1);
            QCLUST(buf, 4, 0, u & 1);
            QCLUST(buf, 4, 1, u & 1);
            __builtin_amdgcn_s_barrier();
        }
    }

    // ---- epilogue: out = acc * scale[n] + bias[n] ----
    // C/D layout: col = lane&15, row = (lane>>4)*4 + reg   (verified, passing R1-R6)
    #pragma unroll
    for (int ni = 0; ni < 4; ++ni) {
        const int gn = n0 + wn * 64 + ni * 16 + lr;
        const float sc = scale[gn];
        const float bi = bias[gn];
        #pragma unroll
        for (int mi = 0; mi < 8; ++mi) {
            const int gm = m0 + wm * 128 + mi * 16 + lk * 4;
            const f32x4 v = acc[mi][ni];
            #pragma unroll
            for (int r = 0; r < 4; ++r)
                out[(size_t)(gm + r) * N_DIM + gn] = v[r] * sc + bi;
        }
    }
#undef STAGE_A
#undef LOADB
#undef QCLUST
#undef VMC
}

// ---------------- fallback: fused dequant GEMM (R1 kernel, known-good) ----------------
__device__ __forceinline__ int swz(int row, int kbyte) {
    return row * 128 + (kbyte ^ ((row & 7) << 4));
}

__global__ __launch_bounds__(256, 2)
void qlin_kernel(const float* __restrict__ x,
                 const int*   __restrict__ wq,
                 const float* __restrict__ scale,
                 const float* __restrict__ bias,
                 float* __restrict__ out)
{
    __shared__ short As[128 * 64];
    __shared__ short Bs[128 * 64];

    const int t  = threadIdx.x;
    const int n0 = blockIdx.x * 128;
    const int m0 = blockIdx.y * 128;

    const int sr = t >> 1;
    const int sh = t & 1;

    const float* ag = x  + (size_t)(m0 + sr) * K_DIM + sh * 32;
    const int*   bg = wq + (size_t)(n0 + sr) * KP    + sh * 16;

    const int lane = t & 63;
    const int wv   = t >> 6;
    const int wm   = wv >> 1;
    const int wn   = wv & 1;
    const int lr   = lane & 15;
    const int lk   = lane >> 4;

    f32x4 acc[4][4];
    #pragma unroll
    for (int i = 0; i < 4; ++i)
        #pragma unroll
        for (int j = 0; j < 4; ++j)
            acc[i][j] = (f32x4){0.f, 0.f, 0.f, 0.f};

    f32x4 ar[8];
    i32x4 br[4];

    #pragma unroll
    for (int i = 0; i < 8; ++i) ar[i] = *(const f32x4*)(ag + i * 4);
    #pragma unroll
    for (int i = 0; i < 4; ++i) br[i] = *(const i32x4*)(bg + i * 4);

    for (int kt = 0; kt < 64; ++kt) {
        #pragma unroll
        for (int c = 0; c < 4; ++c) {
            bf16x8 pa;
            #pragma unroll
            for (int j = 0; j < 8; ++j)
                pa[j] = f2bf(ar[c * 2 + (j >> 2)][j & 3]);
            *(bf16x8*)((char*)As + swz(sr, sh * 64 + c * 16)) = pa;

            bf16x8 pb;
            #pragma unroll
            for (int j = 0; j < 4; ++j) {
                const int q = br[c][j] ^ 0x88;
                const float flo = __builtin_bit_cast(float, 0x4B000000 | (q & 15))        - 8388616.0f;
                const float fhi = __builtin_bit_cast(float, 0x4B000000 | ((q >> 4) & 15)) - 8388616.0f;
                pb[2 * j]     = f2bf(flo);
                pb[2 * j + 1] = f2bf(fhi);
            }
            *(bf16x8*)((char*)Bs + swz(sr, sh * 64 + c * 16)) = pb;
        }
        __syncthreads();

        if (kt + 1 < 64) {
            const float* an = ag + (kt + 1) * 64;
            const int*   bn = bg + (kt + 1) * 32;
            #pragma unroll
            for (int i = 0; i < 8; ++i) ar[i] = *(const f32x4*)(an + i * 4);
            #pragma unroll
            for (int i = 0; i < 4; ++i) br[i] = *(const i32x4*)(bn + i * 4);
        }

        #pragma unroll
        for (int ks = 0; ks < 2; ++ks) {
            const int kb = ks * 64 + lk * 16;
            bf16x8 af2[4], bf2[4];
            #pragma unroll
            for (int mi = 0; mi < 4; ++mi)
                af2[mi] = *(const bf16x8*)((const char*)As + swz(wm * 64 + mi * 16 + lr, kb));
            #pragma unroll
            for (int ni = 0; ni < 4; ++ni)
                bf2[ni] = *(const bf16x8*)((const char*)Bs + swz(wn * 64 + ni * 16 + lr, kb));
            #pragma unroll
            for (int mi = 0; mi < 4; ++mi)
                #pragma unroll
                for (int ni = 0; ni < 4; ++ni)
                    acc[mi][ni] = __builtin_amdgcn_mfma_f32_16x16x32_bf16(
                        af2[mi], bf2[ni], acc[mi][ni], 0, 0, 0);
        }
        __syncthreads();
    }

    #pragma unroll
    for (int ni = 0; ni < 4; ++ni) {
        const int gn = n0 + wn * 64 + ni * 16 + lr;
        const float sc = scale[gn];
        const float bi = bias[gn];
        #pragma unroll
        for (int mi = 0; mi < 4; ++mi) {
            const int gm = m0 + wm * 64 + mi * 16 + lk * 4;
            const f32x4 v = acc[mi][ni];
            #pragma unroll
            for (int r2 = 0; r2 < 4; ++r2)
                out[(size_t)(gm + r2) * N_DIM + gn] = v[r2] * sc + bi;
        }
    }
}

extern "C" void kernel_launch(void* const* d_in, const int* in_sizes, int n_in,
                              void* d_out, int out_size, void* d_ws, size_t ws_size,
                              hipStream_t stream)
{
    const float* x     = (const float*)d_in[0];
    const int*   wq    = (const int*)d_in[1];
    const float* scale = (const float*)d_in[2];
    const float* bias  = (const float*)d_in[3];
    float*       out   = (float*)d_out;

    if (ws_size >= WS_NEED) {
        short* xb = (short*)d_ws;
        char*  wb = (char*)d_ws + A_WS_BYTES;
        cvt_x_kernel<<<16384, 256, 0, stream>>>(x, xb);
        dequant_w_frag<<<22016, 256, 0, stream>>>(wq, (short*)wb);
        const int nwg = (N_DIM / BN) * (M_DIM / BM);   // 43*32 = 1376
        gemm256_kernel<<<nwg, 512, 0, stream>>>(xb, wb, scale, bias, out);
    } else {
        qlin_kernel<<<dim3(N_DIM / 128, M_DIM / 128), 256, 0, stream>>>(x, wq, scale, bias, out);
    }
}